// Round 3
// baseline (3394.591 us; speedup 1.0000x reference)
//
#include <hip/hip_runtime.h>
#include <cstdint>
#include <cstddef>

// Informer ProbSparse decoder layer, f32, correctness-first.
// B=4 L=1024 Dm=1024 H=16 Dh=64 U=U_part=35 FF=4096.
#define B_     4
#define L_     1024
#define DM_    1024
#define H_     16
#define DH_    64
#define U_     35
#define FF_    4096
#define MROWS_ 4096          // B_*L_
#define IDXN_  35840         // L_*U_ random draws per attention

// ---------------- Threefry-2x32-20 (exact JAX semantics) ----------------
__host__ __device__ inline void tf2x32(uint32_t k0, uint32_t k1,
                                       uint32_t x0, uint32_t x1,
                                       uint32_t& y0, uint32_t& y1) {
  const uint32_t ks2 = k0 ^ k1 ^ 0x1BD11BDAu;
  uint32_t v0 = x0 + k0, v1 = x1 + k1;
#define ROTL_(x,d) (((x)<<(d))|((x)>>(32-(d))))
#define RND_(r) { v0 += v1; v1 = ROTL_(v1,(r)); v1 ^= v0; }
  RND_(13) RND_(15) RND_(26) RND_(6)   v0 += k1;  v1 += ks2 + 1u;
  RND_(17) RND_(29) RND_(16) RND_(24)  v0 += ks2; v1 += k0  + 2u;
  RND_(13) RND_(15) RND_(26) RND_(6)   v0 += k0;  v1 += k1  + 3u;
  RND_(17) RND_(29) RND_(16) RND_(24)  v0 += k1;  v1 += ks2 + 4u;
  RND_(13) RND_(15) RND_(26) RND_(6)   v0 += ks2; v1 += k0  + 5u;
#undef RND_
#undef ROTL_
  y0 = v0; y1 = v1;
}

// JAX partitionable threefry random_bits, 32-bit:
//   bits[i] = y0 ^ y1 of threefry(key, (hi32(i), lo32(i)))   [XOR fold]
// idx[i] = bits[i] % 1024 (span=1024 pow2 -> higher_bits contribute 0).
__global__ void idx_kernel(uint32_t k0, uint32_t k1, int* __restrict__ idx) {
  const int i = blockIdx.x * 256 + threadIdx.x;
  if (i >= IDXN_) return;
  uint32_t y0, y1;
  tf2x32(k0, k1, 0u, (uint32_t)i, y0, y1);
  idx[i] = (int)((y0 ^ y1) & 1023u);
}

// ---------------- f32 tiled GEMM: C = A(MxK) @ B(KxN) + bias, opt relu ----
#define GBM 128
#define GBN 128
#define GBK 16
__global__ __launch_bounds__(256) void gemm_f32(
    const float* __restrict__ A, const float* __restrict__ B,
    const float* __restrict__ bias, float* __restrict__ C,
    int M, int N, int K, int relu)
{
  __shared__ float As[GBK][GBM + 4];   // transposed A tile, padded
  __shared__ float Bs[GBK][GBN + 4];
  const int tid = threadIdx.x;
  const int bm = blockIdx.y * GBM;
  const int bn = blockIdx.x * GBN;
  const int tx = tid & 15;       // col group (8 cols)
  const int ty = tid >> 4;       // row group (8 rows)
  const int ar = tid >> 1;       // A-load row 0..127
  const int ac = (tid & 1) * 8;  // A-load col 0 or 8
  float acc[8][8];
#pragma unroll
  for (int i = 0; i < 8; ++i)
#pragma unroll
    for (int j = 0; j < 8; ++j) acc[i][j] = 0.f;

  const float* Aptr = A + (size_t)(bm + ar) * K + ac;
  const float* Bptr = B + (size_t)ty * N + bn + tx * 8;

  for (int kk = 0; kk < K; kk += GBK) {
    float4 a0 = *(const float4*)(Aptr + kk);
    float4 a1 = *(const float4*)(Aptr + kk + 4);
    float4 b0 = *(const float4*)(Bptr + (size_t)kk * N);
    float4 b1 = *(const float4*)(Bptr + (size_t)kk * N + 4);
    As[ac+0][ar] = a0.x; As[ac+1][ar] = a0.y; As[ac+2][ar] = a0.z; As[ac+3][ar] = a0.w;
    As[ac+4][ar] = a1.x; As[ac+5][ar] = a1.y; As[ac+6][ar] = a1.z; As[ac+7][ar] = a1.w;
    *(float4*)&Bs[ty][tx*8]     = b0;
    *(float4*)&Bs[ty][tx*8 + 4] = b1;
    __syncthreads();
#pragma unroll
    for (int k = 0; k < GBK; ++k) {
      float4 xa0 = *(const float4*)&As[k][ty*8];
      float4 xa1 = *(const float4*)&As[k][ty*8+4];
      float4 xb0 = *(const float4*)&Bs[k][tx*8];
      float4 xb1 = *(const float4*)&Bs[k][tx*8+4];
      float av[8] = {xa0.x,xa0.y,xa0.z,xa0.w,xa1.x,xa1.y,xa1.z,xa1.w};
      float bv[8] = {xb0.x,xb0.y,xb0.z,xb0.w,xb1.x,xb1.y,xb1.z,xb1.w};
#pragma unroll
      for (int i = 0; i < 8; ++i)
#pragma unroll
        for (int j = 0; j < 8; ++j) acc[i][j] = fmaf(av[i], bv[j], acc[i][j]);
    }
    __syncthreads();
  }
  float bv[8];
#pragma unroll
  for (int j = 0; j < 8; ++j) bv[j] = bias[bn + tx*8 + j];
#pragma unroll
  for (int i = 0; i < 8; ++i) {
    float o[8];
#pragma unroll
    for (int j = 0; j < 8; ++j) {
      float t = acc[i][j] + bv[j];
      o[j] = relu ? fmaxf(t, 0.f) : t;
    }
    float* crow = C + (size_t)(bm + ty*8 + i) * N + bn + tx*8;
    *(float4*)crow       = make_float4(o[0],o[1],o[2],o[3]);
    *(float4*)(crow + 4) = make_float4(o[4],o[5],o[6],o[7]);
  }
}

// ---------------- sampled QK^T -> M scores --------------------------------
// wave per (b,h,l), lane=d. M = max_s(QKs) - sum_s(QKs)/L_K
__global__ __launch_bounds__(256) void qks_m_kernel(
    const float* __restrict__ Q, const float* __restrict__ K,
    const int* __restrict__ idx, float* __restrict__ Mout)
{
  const int gw   = blockIdx.x * 4 + (threadIdx.x >> 6);
  const int lane = threadIdx.x & 63;
  const int l  = gw & (L_ - 1);
  const int bh = gw >> 10;
  const int h  = bh & (H_ - 1);
  const int b  = bh >> 4;
  const float q = Q[(size_t)(b * L_ + l) * DM_ + h * DH_ + lane];
  float mx = -__builtin_inff();
  float sm = 0.f;
  const int* ip = idx + l * U_;
  for (int s = 0; s < U_; ++s) {
    const int ks = ip[s];
    float p = q * K[(size_t)(b * L_ + ks) * DM_ + h * DH_ + lane];
#pragma unroll
    for (int off = 32; off > 0; off >>= 1) p += __shfl_xor(p, off, 64);
    mx = fmaxf(mx, p);
    sm += p;
  }
  if (lane == 0) Mout[gw] = mx - sm * (1.0f / 1024.0f);
}

// ---------------- top-35 indices per (b,h) (stable, smallest-index ties) --
__global__ __launch_bounds__(256) void topk_kernel(
    const float* __restrict__ M, int* __restrict__ Mtop)
{
  const int bh  = blockIdx.x;
  const int tid = threadIdx.x;
  __shared__ float vals[L_];
  __shared__ float rv[256];
  __shared__ int   ri[256];
  for (int i = tid; i < L_; i += 256) vals[i] = M[(size_t)bh * L_ + i];
  __syncthreads();
  for (int t = 0; t < U_; ++t) {
    float best = -__builtin_inff();
    int   bi   = L_;
    for (int i = tid; i < L_; i += 256) {
      const float v = vals[i];
      if (v > best) { best = v; bi = i; }   // ascending scan => earliest index kept
    }
    rv[tid] = best; ri[tid] = bi;
    __syncthreads();
    for (int s = 128; s > 0; s >>= 1) {
      if (tid < s) {
        if (rv[tid+s] > rv[tid] || (rv[tid+s] == rv[tid] && ri[tid+s] < ri[tid])) {
          rv[tid] = rv[tid+s]; ri[tid] = ri[tid+s];
        }
      }
      __syncthreads();
    }
    if (tid == 0) { Mtop[bh * U_ + t] = ri[0]; vals[ri[0]] = -__builtin_inff(); }
    __syncthreads();
  }
}

// ---------------- full attention for the 35 selected rows -----------------
__global__ __launch_bounds__(256) void attn_kernel(
    const float* __restrict__ Q, const float* __restrict__ K,
    const float* __restrict__ V, const int* __restrict__ Mtop,
    float* __restrict__ ctx_rows, int masked)
{
  const int bhu = blockIdx.x;
  const int u   = bhu % U_;
  const int bh  = bhu / U_;
  const int h   = bh & (H_ - 1);
  const int b   = bh >> 4;
  const int tid = threadIdx.x;
  const int row = Mtop[bh * U_ + u];
  __shared__ float q[DH_];
  __shared__ float sc[L_];
  __shared__ float red[256];
  if (tid < DH_) q[tid] = Q[(size_t)(b * L_ + row) * DM_ + h * DH_ + tid];
  __syncthreads();
  const int kmax = masked ? row : (L_ - 1);
  const int w = tid >> 6, lane = tid & 63;
  for (int k = w; k < L_; k += 4) {
    if (k <= kmax) {
      float p = q[lane] * K[(size_t)(b * L_ + k) * DM_ + h * DH_ + lane];
#pragma unroll
      for (int off = 32; off > 0; off >>= 1) p += __shfl_xor(p, off, 64);
      if (lane == 0) sc[k] = p * 0.125f;            // 1/sqrt(64)
    } else if (lane == 0) {
      sc[k] = -__builtin_inff();
    }
  }
  __syncthreads();
  float mx = -__builtin_inff();
  for (int i = tid; i < L_; i += 256) mx = fmaxf(mx, sc[i]);
  red[tid] = mx; __syncthreads();
  for (int s = 128; s > 0; s >>= 1) { if (tid < s) red[tid] = fmaxf(red[tid], red[tid+s]); __syncthreads(); }
  mx = red[0]; __syncthreads();
  float ssum = 0.f;
  for (int i = tid; i < L_; i += 256) { const float e = expf(sc[i] - mx); sc[i] = e; ssum += e; }
  red[tid] = ssum; __syncthreads();
  for (int s = 128; s > 0; s >>= 1) { if (tid < s) red[tid] += red[tid+s]; __syncthreads(); }
  const float inv = 1.0f / red[0];
  __syncthreads();
  float acc = 0.f;
  for (int k = w; k < L_; k += 4)
    acc += sc[k] * V[(size_t)(b * L_ + k) * DM_ + h * DH_ + lane];
  red[tid] = acc; __syncthreads();
  if (tid < 64) {
    const float r = red[tid] + red[tid+64] + red[tid+128] + red[tid+192];
    ctx_rows[(size_t)bhu * DH_ + tid] = r * inv;
  }
}

// ---------------- cumsum(V) over L per (b,h,d), written (b,l,h,d) ---------
__global__ __launch_bounds__(256) void cumsum_kernel(
    const float* __restrict__ V, float* __restrict__ C)
{
  const int bh = blockIdx.x;
  const int h = bh & (H_ - 1), b = bh >> 4;
  const int d = threadIdx.x & 63, qq = threadIdx.x >> 6;
  __shared__ float chs[4][DH_];
  const size_t base = (size_t)b * L_ * DM_ + h * DH_ + d;
  float acc = 0.f;
  const int l0 = qq * 256;
  for (int l = l0; l < l0 + 256; ++l) acc += V[base + (size_t)l * DM_];
  chs[qq][d] = acc;
  __syncthreads();
  float off = 0.f;
  for (int j = 0; j < qq; ++j) off += chs[j][d];
  acc = off;
  for (int l = l0; l < l0 + 256; ++l) {
    acc += V[base + (size_t)l * DM_];
    C[base + (size_t)l * DM_] = acc;
  }
}

__global__ __launch_bounds__(256) void vmean_kernel(
    const float* __restrict__ V, float* __restrict__ vm)
{
  const int bh = blockIdx.x;
  const int h = bh & (H_ - 1), b = bh >> 4;
  const int d = threadIdx.x & 63, qq = threadIdx.x >> 6;
  __shared__ float chs[4][DH_];
  const size_t base = (size_t)b * L_ * DM_ + h * DH_ + d;
  float acc = 0.f;
  for (int l = qq * 256; l < qq * 256 + 256; ++l) acc += V[base + (size_t)l * DM_];
  chs[qq][d] = acc;
  __syncthreads();
  if (qq == 0)
    vm[bh * DH_ + d] = (chs[0][d] + chs[1][d] + chs[2][d] + chs[3][d]) * (1.0f / 1024.0f);
}

__global__ void fill_kernel(const float* __restrict__ vm, float* __restrict__ C)
{
  const size_t i = (size_t)blockIdx.x * 256 + threadIdx.x;   // over B*L*DM
  const int d = (int)(i & 63);
  const int h = (int)((i >> 6) & (H_ - 1));
  const int b = (int)(i >> 20);
  C[i] = vm[(b * H_ + h) * DH_ + d];
}

__global__ void scatter_kernel(const float* __restrict__ ctx_rows,
                               const int* __restrict__ Mtop, float* __restrict__ C)
{
  const int bhu = blockIdx.x;
  const int u  = bhu % U_;
  const int bh = bhu / U_;
  const int h = bh & (H_ - 1), b = bh >> 4;
  const int row = Mtop[bh * U_ + u];
  C[(size_t)(b * L_ + row) * DM_ + h * DH_ + threadIdx.x] =
      ctx_rows[(size_t)bhu * DH_ + threadIdx.x];
}

// ---------------- LayerNorm(xa + xb), in-place safe -----------------------
__global__ __launch_bounds__(256) void ln_kernel(
    const float* __restrict__ xa, const float* __restrict__ xb,
    const float* __restrict__ g, const float* __restrict__ bt,
    float* __restrict__ out)
{
  const int row = blockIdx.x;
  const int tid = threadIdx.x;
  __shared__ float v[DM_];
  __shared__ float red[256];
  float s = 0.f;
  for (int i = tid; i < DM_; i += 256) {
    const float t = xa[(size_t)row * DM_ + i] + xb[(size_t)row * DM_ + i];
    v[i] = t; s += t;
  }
  red[tid] = s; __syncthreads();
  for (int st = 128; st > 0; st >>= 1) { if (tid < st) red[tid] += red[tid+st]; __syncthreads(); }
  const float mean = red[0] * (1.0f / DM_);
  __syncthreads();
  float s2 = 0.f;
  for (int i = tid; i < DM_; i += 256) { const float dd = v[i] - mean; s2 += dd * dd; }
  red[tid] = s2; __syncthreads();
  for (int st = 128; st > 0; st >>= 1) { if (tid < st) red[tid] += red[tid+st]; __syncthreads(); }
  const float rstd = rsqrtf(red[0] * (1.0f / DM_) + 1e-5f);
  __syncthreads();
  for (int i = tid; i < DM_; i += 256)
    out[(size_t)row * DM_ + i] = (v[i] - mean) * rstd * g[i] + bt[i];
}

// ---------------- host orchestration --------------------------------------
extern "C" void kernel_launch(void* const* d_in, const int* in_sizes, int n_in,
                              void* d_out, int out_size, void* d_ws, size_t ws_size,
                              hipStream_t stream)
{
  (void)in_sizes; (void)n_in; (void)out_size; (void)ws_size;
  const float* x    = (const float*)d_in[0];
  const float* enc  = (const float*)d_in[1];
  const float* saWq = (const float*)d_in[2];  const float* sabq = (const float*)d_in[3];
  const float* saWk = (const float*)d_in[4];  const float* sabk = (const float*)d_in[5];
  const float* saWv = (const float*)d_in[6];  const float* sabv = (const float*)d_in[7];
  const float* saWo = (const float*)d_in[8];  const float* sabo = (const float*)d_in[9];
  const float* caWq = (const float*)d_in[10]; const float* cabq = (const float*)d_in[11];
  const float* caWk = (const float*)d_in[12]; const float* cabk = (const float*)d_in[13];
  const float* caWv = (const float*)d_in[14]; const float* cabv = (const float*)d_in[15];
  const float* caWo = (const float*)d_in[16]; const float* cabo = (const float*)d_in[17];
  const float* fW1  = (const float*)d_in[18]; const float* fb1  = (const float*)d_in[19];
  const float* fW2  = (const float*)d_in[20]; const float* fb2  = (const float*)d_in[21];
  const float* l1g  = (const float*)d_in[22]; const float* l1b  = (const float*)d_in[23];
  const float* l2g  = (const float*)d_in[24]; const float* l2b  = (const float*)d_in[25];
  const float* l3g  = (const float*)d_in[26]; const float* l3b  = (const float*)d_in[27];

  float* ws = (float*)d_ws;
  const size_t SL = (size_t)MROWS_ * DM_;      // 4M floats / 16 MB
  float* bufQ   = ws;
  float* bufK   = ws + SL;
  float* bufV   = ws + 2 * SL;
  float* bufC   = ws + 3 * SL;
  float* xcur   = ws + 4 * SL;
  float* tmp    = ws + 5 * SL;
  float* hidden = ws;                           // FFN stage reuses slots 0..3 (64 MB)
  float* smallp = ws + 6 * SL;
  int*   idxb = (int*)smallp;                                // 35840
  float* Mbuf = smallp + 36864;                              // 65536
  int*   Mtop = (int*)(smallp + 36864 + 65536);              // 2240 (pad to 2304)
  float* ctxr = smallp + 36864 + 65536 + 2304;               // 2240*64
  float* vm   = ctxr + 143360;                               // 1024

  // --- JAX partitionable-threefry key ladder ---
  // key(42) = (0,42). split(key)[j] = full block of threefry(key, (0, j)).
  // randint(key,...) internally: ka, kb = split(key); lower_bits from kb.
  // 32-bit random_bits (partitionable) = y0 ^ y1 of threefry(kb, (0, i)).
  uint32_t k1a, k1b, k2a, k2b;
  tf2x32(0u, 42u, 0u, 0u, k1a, k1b);   // k1 = split(key)[0]
  tf2x32(0u, 42u, 0u, 1u, k2a, k2b);   // k2 = split(key)[1]
  uint32_t kb1a, kb1b, kb2a, kb2b;
  tf2x32(k1a, k1b, 0u, 1u, kb1a, kb1b);  // randint-internal split(k1)[1]
  tf2x32(k2a, k2b, 0u, 1u, kb2a, kb2b);  // randint-internal split(k2)[1]

  const dim3 thr(256);
  const dim3 gP(DM_ / GBN, MROWS_ / GBM);     // (8,32)
  const dim3 gF1(FF_ / GBN, MROWS_ / GBM);    // (32,32)
  const int gIdx = (IDXN_ + 255) / 256;

  // ---- self attention (masked) ----
  gemm_f32<<<gP, thr, 0, stream>>>(x, saWq, sabq, bufQ, MROWS_, DM_, DM_, 0);
  gemm_f32<<<gP, thr, 0, stream>>>(x, saWk, sabk, bufK, MROWS_, DM_, DM_, 0);
  gemm_f32<<<gP, thr, 0, stream>>>(x, saWv, sabv, bufV, MROWS_, DM_, DM_, 0);
  idx_kernel<<<gIdx, thr, 0, stream>>>(kb1a, kb1b, idxb);
  qks_m_kernel<<<(B_ * H_ * L_) / 4, thr, 0, stream>>>(bufQ, bufK, idxb, Mbuf);
  topk_kernel<<<B_ * H_, thr, 0, stream>>>(Mbuf, Mtop);
  attn_kernel<<<B_ * H_ * U_, thr, 0, stream>>>(bufQ, bufK, bufV, Mtop, ctxr, 1);
  cumsum_kernel<<<B_ * H_, thr, 0, stream>>>(bufV, bufC);
  scatter_kernel<<<B_ * H_ * U_, dim3(64), 0, stream>>>(ctxr, Mtop, bufC);
  gemm_f32<<<gP, thr, 0, stream>>>(bufC, saWo, sabo, tmp, MROWS_, DM_, DM_, 0);
  ln_kernel<<<MROWS_, thr, 0, stream>>>(x, tmp, l1g, l1b, xcur);

  // ---- cross attention (unmasked) ----
  gemm_f32<<<gP, thr, 0, stream>>>(xcur, caWq, cabq, bufQ, MROWS_, DM_, DM_, 0);
  gemm_f32<<<gP, thr, 0, stream>>>(enc,  caWk, cabk, bufK, MROWS_, DM_, DM_, 0);
  gemm_f32<<<gP, thr, 0, stream>>>(enc,  caWv, cabv, bufV, MROWS_, DM_, DM_, 0);
  idx_kernel<<<gIdx, thr, 0, stream>>>(kb2a, kb2b, idxb);
  qks_m_kernel<<<(B_ * H_ * L_) / 4, thr, 0, stream>>>(bufQ, bufK, idxb, Mbuf);
  topk_kernel<<<B_ * H_, thr, 0, stream>>>(Mbuf, Mtop);
  attn_kernel<<<B_ * H_ * U_, thr, 0, stream>>>(bufQ, bufK, bufV, Mtop, ctxr, 0);
  vmean_kernel<<<B_ * H_, thr, 0, stream>>>(bufV, vm);
  fill_kernel<<<(int)(SL / 256), thr, 0, stream>>>(vm, bufC);
  scatter_kernel<<<B_ * H_ * U_, dim3(64), 0, stream>>>(ctxr, Mtop, bufC);
  gemm_f32<<<gP, thr, 0, stream>>>(bufC, caWo, cabo, tmp, MROWS_, DM_, DM_, 0);
  ln_kernel<<<MROWS_, thr, 0, stream>>>(xcur, tmp, l2g, l2b, xcur);   // in-place (row cached in LDS)

  // ---- FFN ----
  gemm_f32<<<gF1, thr, 0, stream>>>(xcur, fW1, fb1, hidden, MROWS_, FF_, DM_, 1);
  gemm_f32<<<gP, thr, 0, stream>>>(hidden, fW2, fb2, tmp, MROWS_, DM_, FF_, 0);
  ln_kernel<<<MROWS_, thr, 0, stream>>>(xcur, tmp, l3g, l3b, (float*)d_out);
}

// Round 4
// 1996.944 us; speedup vs baseline: 1.6999x; 1.6999x over previous
//
#include <hip/hip_runtime.h>
#include <cstdint>
#include <cstddef>

// Informer ProbSparse decoder layer. GEMMs via split-bf16 MFMA emulation.
// B=4 L=1024 Dm=1024 H=16 Dh=64 U=U_part=35 FF=4096.
#define B_     4
#define L_     1024
#define DM_    1024
#define H_     16
#define DH_    64
#define U_     35
#define FF_    4096
#define MROWS_ 4096          // B_*L_
#define IDXN_  35840         // L_*U_ random draws per attention

typedef __attribute__((ext_vector_type(8))) short bf16x8;
typedef __attribute__((ext_vector_type(4))) float f32x4;

// ---------------- Threefry-2x32-20 (exact JAX semantics) ----------------
__host__ __device__ inline void tf2x32(uint32_t k0, uint32_t k1,
                                       uint32_t x0, uint32_t x1,
                                       uint32_t& y0, uint32_t& y1) {
  const uint32_t ks2 = k0 ^ k1 ^ 0x1BD11BDAu;
  uint32_t v0 = x0 + k0, v1 = x1 + k1;
#define ROTL_(x,d) (((x)<<(d))|((x)>>(32-(d))))
#define RND_(r) { v0 += v1; v1 = ROTL_(v1,(r)); v1 ^= v0; }
  RND_(13) RND_(15) RND_(26) RND_(6)   v0 += k1;  v1 += ks2 + 1u;
  RND_(17) RND_(29) RND_(16) RND_(24)  v0 += ks2; v1 += k0  + 2u;
  RND_(13) RND_(15) RND_(26) RND_(6)   v0 += k0;  v1 += k1  + 3u;
  RND_(17) RND_(29) RND_(16) RND_(24)  v0 += k1;  v1 += ks2 + 4u;
  RND_(13) RND_(15) RND_(26) RND_(6)   v0 += ks2; v1 += k0  + 5u;
#undef RND_
#undef ROTL_
  y0 = v0; y1 = v1;
}

// JAX partitionable threefry random_bits, 32-bit: bits[i] = y0 ^ y1 (XOR fold).
__global__ void idx_kernel(uint32_t k0, uint32_t k1, int* __restrict__ idx) {
  const int i = blockIdx.x * 256 + threadIdx.x;
  if (i >= IDXN_) return;
  uint32_t y0, y1;
  tf2x32(k0, k1, 0u, (uint32_t)i, y0, y1);
  idx[i] = (int)((y0 ^ y1) & 1023u);
}

// ---------------- split-bf16 MFMA GEMM ------------------------------------
// C(MxN) = A(MxK) @ B(KxN) + bias, optional relu.
// f32 emulated as sum of bf16 limbs; WAYS=2: 3 MFMA terms (~2^-16 rel err);
// WAYS=3: 6 terms (~2^-25 rel err, f32-equivalent -> safe for top-k selection).
// Tile 128x128, BK=32, 256 threads = 4 waves (2x2), 4x4 16x16x32 frags/wave.
// LDS tiles [128 rows][32 k] bf16, 16B-chunk XOR swizzle: chunk ^= (row>>1)&3
// -> minimum bank cost on both ds_write_b128 (stage) and ds_read_b128 (frags).

struct Gemm3 {
  const float* A[3];
  const float* B[3];
  const float* bias[3];
  float*       C[3];
};

__device__ __forceinline__ uint32_t f32bits(float x) {
  union { float f; uint32_t u; } c; c.f = x; return c.u;
}
__device__ __forceinline__ float bitsf32(uint32_t u) {
  union { uint32_t u; float f; } c; c.u = u; return c.f;
}
__device__ __forceinline__ uint32_t bf16rne(float x) {
  const uint32_t u = f32bits(x);
  return (u + 0x7FFFu + ((u >> 16) & 1u)) >> 16;
}

__device__ __forceinline__ void load_a16(const float* p, float (&v)[16]) {
  const float4* q = (const float4*)p;
  float4 x0 = q[0], x1 = q[1], x2 = q[2], x3 = q[3];
  v[0]=x0.x; v[1]=x0.y; v[2]=x0.z; v[3]=x0.w;
  v[4]=x1.x; v[5]=x1.y; v[6]=x1.z; v[7]=x1.w;
  v[8]=x2.x; v[9]=x2.y; v[10]=x2.z; v[11]=x2.w;
  v[12]=x3.x; v[13]=x3.y; v[14]=x3.z; v[15]=x3.w;
}
__device__ __forceinline__ void load_b16(const float* p, int N, float (&v)[16]) {
#pragma unroll
  for (int j = 0; j < 16; ++j) v[j] = p[(size_t)j * N];
}

template<int WAYS>
__device__ __forceinline__ void split_write(const float (&v)[16], int sr, int skh,
                                            uint32_t* H, uint32_t* Mi, uint32_t* L)
{
  uint32_t hp[8], lp[8], mp[8];
#pragma unroll
  for (int e = 0; e < 8; ++e) {
    const float a0 = v[2*e], a1 = v[2*e+1];
    const uint32_t h0 = f32bits(a0) & 0xFFFF0000u;
    const uint32_t h1 = f32bits(a1) & 0xFFFF0000u;
    hp[e] = (h0 >> 16) | h1;
    float r0 = a0 - bitsf32(h0);
    float r1 = a1 - bitsf32(h1);
    if (WAYS == 3) {
      const uint32_t m0 = f32bits(r0) & 0xFFFF0000u;
      const uint32_t m1 = f32bits(r1) & 0xFFFF0000u;
      mp[e] = (m0 >> 16) | m1;
      r0 -= bitsf32(m0); r1 -= bitsf32(m1);
    }
    lp[e] = bf16rne(r0) | (bf16rne(r1) << 16);
  }
  const int q  = (sr >> 1) & 3;
  const int b0 = sr * 64 + (((skh * 2 + 0) ^ q) << 4);
  const int b1 = sr * 64 + (((skh * 2 + 1) ^ q) << 4);
  *(uint4*)((char*)H + b0) = make_uint4(hp[0], hp[1], hp[2], hp[3]);
  *(uint4*)((char*)H + b1) = make_uint4(hp[4], hp[5], hp[6], hp[7]);
  if (WAYS == 3) {
    *(uint4*)((char*)Mi + b0) = make_uint4(mp[0], mp[1], mp[2], mp[3]);
    *(uint4*)((char*)Mi + b1) = make_uint4(mp[4], mp[5], mp[6], mp[7]);
  }
  *(uint4*)((char*)L + b0) = make_uint4(lp[0], lp[1], lp[2], lp[3]);
  *(uint4*)((char*)L + b1) = make_uint4(lp[4], lp[5], lp[6], lp[7]);
}

template<int WAYS, bool RELU, bool LOAD_EARLY>
__global__ __launch_bounds__(256, 2) void gemm_mfma(Gemm3 g, int K, int N)
{
  constexpr int NB = (WAYS == 3) ? 2048 : 4;
  __shared__ uint32_t AhL[2048], BhL[2048], AlL[2048], BlL[2048];
  __shared__ uint32_t AmL[NB], BmL[NB];

  const int z = blockIdx.z;
  const float* __restrict__ A    = g.A[z];
  const float* __restrict__ B    = g.B[z];
  const float* __restrict__ bias = g.bias[z];
  float* __restrict__       C    = g.C[z];
  const int bm = blockIdx.y * 128, bn = blockIdx.x * 128;

  const int t   = threadIdx.x;
  const int sr  = t >> 1, skh = t & 1;         // staging: row/col 0..127, k-half
  const int lane = t & 63, wid = t >> 6;
  const int wr = wid >> 1, wc = wid & 1;
  const int kg = lane >> 4, l15 = lane & 15;

  int aoff[4], boff[4];
#pragma unroll
  for (int m = 0; m < 4; ++m) {
    const int row = wr * 64 + m * 16 + l15;
    aoff[m] = row * 64 + ((kg ^ ((row >> 1) & 3)) << 4);
    const int col = wc * 64 + m * 16 + l15;
    boff[m] = col * 64 + ((kg ^ ((col >> 1) & 3)) << 4);
  }

  f32x4 acc[4][4];
#pragma unroll
  for (int m = 0; m < 4; ++m)
#pragma unroll
    for (int n = 0; n < 4; ++n) acc[m][n] = (f32x4){0.f, 0.f, 0.f, 0.f};

  float va[16], vb[16];
  load_a16(A + (size_t)(bm + sr) * K + skh * 16, va);
  load_b16(B + (size_t)(skh * 16) * N + bn + sr, N, vb);

  for (int kk = 0; kk < K; kk += 32) {
    __syncthreads();
    split_write<WAYS>(va, sr, skh, AhL, AmL, AlL);
    split_write<WAYS>(vb, sr, skh, BhL, BmL, BlL);
    __syncthreads();
    const bool more = (kk + 32 < K);
    if (LOAD_EARLY && more) {
      load_a16(A + (size_t)(bm + sr) * K + kk + 32 + skh * 16, va);
      load_b16(B + (size_t)(kk + 32 + skh * 16) * N + bn + sr, N, vb);
    }
    bf16x8 ah[4], al[4], bh[4], bl[4], am[4], bmf[4];
#pragma unroll
    for (int m = 0; m < 4; ++m) {
      ah[m] = *(const bf16x8*)((const char*)AhL + aoff[m]);
      al[m] = *(const bf16x8*)((const char*)AlL + aoff[m]);
      bh[m] = *(const bf16x8*)((const char*)BhL + boff[m]);
      bl[m] = *(const bf16x8*)((const char*)BlL + boff[m]);
      if (WAYS == 3) {
        am[m]  = *(const bf16x8*)((const char*)AmL + aoff[m]);
        bmf[m] = *(const bf16x8*)((const char*)BmL + boff[m]);
      }
    }
#pragma unroll
    for (int m = 0; m < 4; ++m)
#pragma unroll
      for (int n = 0; n < 4; ++n) {
        acc[m][n] = __builtin_amdgcn_mfma_f32_16x16x32_bf16(ah[m], bh[n], acc[m][n], 0, 0, 0);
        if (WAYS == 3) {
          acc[m][n] = __builtin_amdgcn_mfma_f32_16x16x32_bf16(ah[m], bmf[n], acc[m][n], 0, 0, 0);
          acc[m][n] = __builtin_amdgcn_mfma_f32_16x16x32_bf16(am[m], bh[n],  acc[m][n], 0, 0, 0);
          acc[m][n] = __builtin_amdgcn_mfma_f32_16x16x32_bf16(am[m], bmf[n], acc[m][n], 0, 0, 0);
        }
        acc[m][n] = __builtin_amdgcn_mfma_f32_16x16x32_bf16(ah[m], bl[n], acc[m][n], 0, 0, 0);
        acc[m][n] = __builtin_amdgcn_mfma_f32_16x16x32_bf16(al[m], bh[n], acc[m][n], 0, 0, 0);
      }
    if (!LOAD_EARLY && more) {
      load_a16(A + (size_t)(bm + sr) * K + kk + 32 + skh * 16, va);
      load_b16(B + (size_t)(kk + 32 + skh * 16) * N + bn + sr, N, vb);
    }
  }

  // epilogue: C/D frag layout col=lane&15, row=(lane>>4)*4+q  [m89 verified]
#pragma unroll
  for (int m = 0; m < 4; ++m) {
    const int row0 = bm + wr * 64 + m * 16 + (lane >> 4) * 4;
#pragma unroll
    for (int n = 0; n < 4; ++n) {
      const int col = bn + wc * 64 + n * 16 + l15;
      const float bv = bias[col];
      const f32x4 a = acc[m][n];
#pragma unroll
      for (int q2 = 0; q2 < 4; ++q2) {
        float o = a[q2] + bv;
        if (RELU) o = fmaxf(o, 0.f);
        C[(size_t)(row0 + q2) * N + col] = o;
      }
    }
  }
}

// ---------------- sampled QK^T -> M scores --------------------------------
__global__ __launch_bounds__(256) void qks_m_kernel(
    const float* __restrict__ Q, const float* __restrict__ K,
    const int* __restrict__ idx, float* __restrict__ Mout)
{
  const int gw   = blockIdx.x * 4 + (threadIdx.x >> 6);
  const int lane = threadIdx.x & 63;
  const int l  = gw & (L_ - 1);
  const int bh = gw >> 10;
  const int h  = bh & (H_ - 1);
  const int b  = bh >> 4;
  const float q = Q[(size_t)(b * L_ + l) * DM_ + h * DH_ + lane];
  float mx = -__builtin_inff();
  float sm = 0.f;
  const int* ip = idx + l * U_;
  for (int s = 0; s < U_; ++s) {
    const int ks = ip[s];
    float p = q * K[(size_t)(b * L_ + ks) * DM_ + h * DH_ + lane];
#pragma unroll
    for (int off = 32; off > 0; off >>= 1) p += __shfl_xor(p, off, 64);
    mx = fmaxf(mx, p);
    sm += p;
  }
  if (lane == 0) Mout[gw] = mx - sm * (1.0f / 1024.0f);
}

// ---------------- top-35 indices per (b,h) --------------------------------
__global__ __launch_bounds__(256) void topk_kernel(
    const float* __restrict__ M, int* __restrict__ Mtop)
{
  const int bh  = blockIdx.x;
  const int tid = threadIdx.x;
  __shared__ float vals[L_];
  __shared__ float rv[256];
  __shared__ int   ri[256];
  for (int i = tid; i < L_; i += 256) vals[i] = M[(size_t)bh * L_ + i];
  __syncthreads();
  for (int t = 0; t < U_; ++t) {
    float best = -__builtin_inff();
    int   bi   = L_;
    for (int i = tid; i < L_; i += 256) {
      const float v = vals[i];
      if (v > best) { best = v; bi = i; }
    }
    rv[tid] = best; ri[tid] = bi;
    __syncthreads();
    for (int s = 128; s > 0; s >>= 1) {
      if (tid < s) {
        if (rv[tid+s] > rv[tid] || (rv[tid+s] == rv[tid] && ri[tid+s] < ri[tid])) {
          rv[tid] = rv[tid+s]; ri[tid] = ri[tid+s];
        }
      }
      __syncthreads();
    }
    if (tid == 0) { Mtop[bh * U_ + t] = ri[0]; vals[ri[0]] = -__builtin_inff(); }
    __syncthreads();
  }
}

// ---------------- full attention for the 35 selected rows -----------------
__global__ __launch_bounds__(256) void attn_kernel(
    const float* __restrict__ Q, const float* __restrict__ K,
    const float* __restrict__ V, const int* __restrict__ Mtop,
    float* __restrict__ ctx_rows, int masked)
{
  const int bhu = blockIdx.x;
  const int u   = bhu % U_;
  const int bh  = bhu / U_;
  const int h   = bh & (H_ - 1);
  const int b   = bh >> 4;
  const int tid = threadIdx.x;
  const int row = Mtop[bh * U_ + u];
  __shared__ float q[DH_];
  __shared__ float sc[L_];
  __shared__ float red[256];
  if (tid < DH_) q[tid] = Q[(size_t)(b * L_ + row) * DM_ + h * DH_ + tid];
  __syncthreads();
  const int kmax = masked ? row : (L_ - 1);
  const int w = tid >> 6, lane = tid & 63;
  for (int k = w; k < L_; k += 4) {
    if (k <= kmax) {
      float p = q[lane] * K[(size_t)(b * L_ + k) * DM_ + h * DH_ + lane];
#pragma unroll
      for (int off = 32; off > 0; off >>= 1) p += __shfl_xor(p, off, 64);
      if (lane == 0) sc[k] = p * 0.125f;
    } else if (lane == 0) {
      sc[k] = -__builtin_inff();
    }
  }
  __syncthreads();
  float mx = -__builtin_inff();
  for (int i = tid; i < L_; i += 256) mx = fmaxf(mx, sc[i]);
  red[tid] = mx; __syncthreads();
  for (int s = 128; s > 0; s >>= 1) { if (tid < s) red[tid] = fmaxf(red[tid], red[tid+s]); __syncthreads(); }
  mx = red[0]; __syncthreads();
  float ssum = 0.f;
  for (int i = tid; i < L_; i += 256) { const float e = expf(sc[i] - mx); sc[i] = e; ssum += e; }
  red[tid] = ssum; __syncthreads();
  for (int s = 128; s > 0; s >>= 1) { if (tid < s) red[tid] += red[tid+s]; __syncthreads(); }
  const float inv = 1.0f / red[0];
  __syncthreads();
  float acc = 0.f;
  for (int k = w; k < L_; k += 4)
    acc += sc[k] * V[(size_t)(b * L_ + k) * DM_ + h * DH_ + lane];
  red[tid] = acc; __syncthreads();
  if (tid < 64) {
    const float r = red[tid] + red[tid+64] + red[tid+128] + red[tid+192];
    ctx_rows[(size_t)bhu * DH_ + tid] = r * inv;
  }
}

// ---------------- cumsum(V) over L per (b,h,d) ----------------------------
__global__ __launch_bounds__(256) void cumsum_kernel(
    const float* __restrict__ V, float* __restrict__ C)
{
  const int bh = blockIdx.x;
  const int h = bh & (H_ - 1), b = bh >> 4;
  const int d = threadIdx.x & 63, qq = threadIdx.x >> 6;
  __shared__ float chs[4][DH_];
  const size_t base = (size_t)b * L_ * DM_ + h * DH_ + d;
  float acc = 0.f;
  const int l0 = qq * 256;
  for (int l = l0; l < l0 + 256; ++l) acc += V[base + (size_t)l * DM_];
  chs[qq][d] = acc;
  __syncthreads();
  float off = 0.f;
  for (int j = 0; j < qq; ++j) off += chs[j][d];
  acc = off;
  for (int l = l0; l < l0 + 256; ++l) {
    acc += V[base + (size_t)l * DM_];
    C[base + (size_t)l * DM_] = acc;
  }
}

__global__ __launch_bounds__(256) void vmean_kernel(
    const float* __restrict__ V, float* __restrict__ vm)
{
  const int bh = blockIdx.x;
  const int h = bh & (H_ - 1), b = bh >> 4;
  const int d = threadIdx.x & 63, qq = threadIdx.x >> 6;
  __shared__ float chs[4][DH_];
  const size_t base = (size_t)b * L_ * DM_ + h * DH_ + d;
  float acc = 0.f;
  for (int l = qq * 256; l < qq * 256 + 256; ++l) acc += V[base + (size_t)l * DM_];
  chs[qq][d] = acc;
  __syncthreads();
  if (qq == 0)
    vm[bh * DH_ + d] = (chs[0][d] + chs[1][d] + chs[2][d] + chs[3][d]) * (1.0f / 1024.0f);
}

__global__ void fill_kernel(const float* __restrict__ vm, float* __restrict__ C)
{
  const size_t i = (size_t)blockIdx.x * 256 + threadIdx.x;
  const int d = (int)(i & 63);
  const int h = (int)((i >> 6) & (H_ - 1));
  const int b = (int)(i >> 20);
  C[i] = vm[(b * H_ + h) * DH_ + d];
}

__global__ void scatter_kernel(const float* __restrict__ ctx_rows,
                               const int* __restrict__ Mtop, float* __restrict__ C)
{
  const int bhu = blockIdx.x;
  const int u  = bhu % U_;
  const int bh = bhu / U_;
  const int h = bh & (H_ - 1), b = bh >> 4;
  const int row = Mtop[bh * U_ + u];
  C[(size_t)(b * L_ + row) * DM_ + h * DH_ + threadIdx.x] =
      ctx_rows[(size_t)bhu * DH_ + threadIdx.x];
}

// ---------------- LayerNorm(xa + xb) --------------------------------------
__global__ __launch_bounds__(256) void ln_kernel(
    const float* __restrict__ xa, const float* __restrict__ xb,
    const float* __restrict__ g, const float* __restrict__ bt,
    float* __restrict__ out)
{
  const int row = blockIdx.x;
  const int tid = threadIdx.x;
  __shared__ float v[DM_];
  __shared__ float red[256];
  float s = 0.f;
  for (int i = tid; i < DM_; i += 256) {
    const float t = xa[(size_t)row * DM_ + i] + xb[(size_t)row * DM_ + i];
    v[i] = t; s += t;
  }
  red[tid] = s; __syncthreads();
  for (int st = 128; st > 0; st >>= 1) { if (tid < st) red[tid] += red[tid+st]; __syncthreads(); }
  const float mean = red[0] * (1.0f / DM_);
  __syncthreads();
  float s2 = 0.f;
  for (int i = tid; i < DM_; i += 256) { const float dd = v[i] - mean; s2 += dd * dd; }
  red[tid] = s2; __syncthreads();
  for (int st = 128; st > 0; st >>= 1) { if (tid < st) red[tid] += red[tid+st]; __syncthreads(); }
  const float rstd = rsqrtf(red[0] * (1.0f / DM_) + 1e-5f);
  __syncthreads();
  for (int i = tid; i < DM_; i += 256)
    out[(size_t)row * DM_ + i] = (v[i] - mean) * rstd * g[i] + bt[i];
}

// ---------------- host orchestration --------------------------------------
extern "C" void kernel_launch(void* const* d_in, const int* in_sizes, int n_in,
                              void* d_out, int out_size, void* d_ws, size_t ws_size,
                              hipStream_t stream)
{
  (void)in_sizes; (void)n_in; (void)out_size; (void)ws_size;
  const float* x    = (const float*)d_in[0];
  const float* enc  = (const float*)d_in[1];
  const float* saWq = (const float*)d_in[2];  const float* sabq = (const float*)d_in[3];
  const float* saWk = (const float*)d_in[4];  const float* sabk = (const float*)d_in[5];
  const float* saWv = (const float*)d_in[6];  const float* sabv = (const float*)d_in[7];
  const float* saWo = (const float*)d_in[8];  const float* sabo = (const float*)d_in[9];
  const float* caWq = (const float*)d_in[10]; const float* cabq = (const float*)d_in[11];
  const float* caWk = (const float*)d_in[12]; const float* cabk = (const float*)d_in[13];
  const float* caWv = (const float*)d_in[14]; const float* cabv = (const float*)d_in[15];
  const float* caWo = (const float*)d_in[16]; const float* cabo = (const float*)d_in[17];
  const float* fW1  = (const float*)d_in[18]; const float* fb1  = (const float*)d_in[19];
  const float* fW2  = (const float*)d_in[20]; const float* fb2  = (const float*)d_in[21];
  const float* l1g  = (const float*)d_in[22]; const float* l1b  = (const float*)d_in[23];
  const float* l2g  = (const float*)d_in[24]; const float* l2b  = (const float*)d_in[25];
  const float* l3g  = (const float*)d_in[26]; const float* l3b  = (const float*)d_in[27];

  float* ws = (float*)d_ws;
  const size_t SL = (size_t)MROWS_ * DM_;      // 4M floats / 16 MB
  float* bufQ   = ws;
  float* bufK   = ws + SL;
  float* bufV   = ws + 2 * SL;
  float* bufC   = ws + 3 * SL;
  float* xcur   = ws + 4 * SL;
  float* tmp    = ws + 5 * SL;
  float* hidden = ws;                           // FFN stage reuses slots 0..3 (64 MB)
  float* smallp = ws + 6 * SL;
  int*   idxb = (int*)smallp;                                // 35840
  float* Mbuf = smallp + 36864;                              // 65536
  int*   Mtop = (int*)(smallp + 36864 + 65536);              // 2240 (pad to 2304)
  float* ctxr = smallp + 36864 + 65536 + 2304;               // 2240*64
  float* vm   = ctxr + 143360;                               // 1024

  // --- JAX partitionable-threefry key ladder (verified round 3) ---
  uint32_t k1a, k1b, k2a, k2b;
  tf2x32(0u, 42u, 0u, 0u, k1a, k1b);   // k1 = split(key)[0]
  tf2x32(0u, 42u, 0u, 1u, k2a, k2b);   // k2 = split(key)[1]
  uint32_t kb1a, kb1b, kb2a, kb2b;
  tf2x32(k1a, k1b, 0u, 1u, kb1a, kb1b);  // randint-internal split(k1)[1]
  tf2x32(k2a, k2b, 0u, 1u, kb2a, kb2b);  // randint-internal split(k2)[1]

  const dim3 thr(256);
  const int gIdx = (IDXN_ + 255) / 256;

  const dim3 gP1(DM_ / 128, MROWS_ / 128, 1);   // (8,32,1)
  const dim3 gP3(DM_ / 128, MROWS_ / 128, 3);   // (8,32,3)
  const dim3 gF1(FF_ / 128, MROWS_ / 128, 1);   // (32,32,1)

  // ---- self attention (masked) ----
  {
    Gemm3 g = {{x, x, x}, {saWq, saWk, saWv}, {sabq, sabk, sabv}, {bufQ, bufK, bufV}};
    gemm_mfma<3, false, false><<<gP3, thr, 0, stream>>>(g, DM_, DM_);
  }
  idx_kernel<<<gIdx, thr, 0, stream>>>(kb1a, kb1b, idxb);
  qks_m_kernel<<<(B_ * H_ * L_) / 4, thr, 0, stream>>>(bufQ, bufK, idxb, Mbuf);
  topk_kernel<<<B_ * H_, thr, 0, stream>>>(Mbuf, Mtop);
  attn_kernel<<<B_ * H_ * U_, thr, 0, stream>>>(bufQ, bufK, bufV, Mtop, ctxr, 1);
  cumsum_kernel<<<B_ * H_, thr, 0, stream>>>(bufV, bufC);
  scatter_kernel<<<B_ * H_ * U_, dim3(64), 0, stream>>>(ctxr, Mtop, bufC);
  {
    Gemm3 g = {{bufC, nullptr, nullptr}, {saWo, nullptr, nullptr},
               {sabo, nullptr, nullptr}, {tmp, nullptr, nullptr}};
    gemm_mfma<2, false, true><<<gP1, thr, 0, stream>>>(g, DM_, DM_);
  }
  ln_kernel<<<MROWS_, thr, 0, stream>>>(x, tmp, l1g, l1b, xcur);

  // ---- cross attention (unmasked) ----
  {
    Gemm3 g = {{xcur, enc, enc}, {caWq, caWk, caWv}, {cabq, cabk, cabv}, {bufQ, bufK, bufV}};
    gemm_mfma<3, false, false><<<gP3, thr, 0, stream>>>(g, DM_, DM_);
  }
  idx_kernel<<<gIdx, thr, 0, stream>>>(kb2a, kb2b, idxb);
  qks_m_kernel<<<(B_ * H_ * L_) / 4, thr, 0, stream>>>(bufQ, bufK, idxb, Mbuf);
  topk_kernel<<<B_ * H_, thr, 0, stream>>>(Mbuf, Mtop);
  attn_kernel<<<B_ * H_ * U_, thr, 0, stream>>>(bufQ, bufK, bufV, Mtop, ctxr, 0);
  vmean_kernel<<<B_ * H_, thr, 0, stream>>>(bufV, vm);
  fill_kernel<<<(int)(SL / 256), thr, 0, stream>>>(vm, bufC);
  scatter_kernel<<<B_ * H_ * U_, dim3(64), 0, stream>>>(ctxr, Mtop, bufC);
  {
    Gemm3 g = {{bufC, nullptr, nullptr}, {caWo, nullptr, nullptr},
               {cabo, nullptr, nullptr}, {tmp, nullptr, nullptr}};
    gemm_mfma<2, false, true><<<gP1, thr, 0, stream>>>(g, DM_, DM_);
  }
  ln_kernel<<<MROWS_, thr, 0, stream>>>(xcur, tmp, l2g, l2b, xcur);

  // ---- FFN ----
  {
    Gemm3 g = {{xcur, nullptr, nullptr}, {fW1, nullptr, nullptr},
               {fb1, nullptr, nullptr}, {hidden, nullptr, nullptr}};
    gemm_mfma<2, true, true><<<gF1, thr, 0, stream>>>(g, DM_, FF_);
  }
  {
    Gemm3 g = {{hidden, nullptr, nullptr}, {fW2, nullptr, nullptr},
               {fb2, nullptr, nullptr}, {tmp, nullptr, nullptr}};
    gemm_mfma<2, false, true><<<gP1, thr, 0, stream>>>(g, FF_, DM_);
  }
  ln_kernel<<<MROWS_, thr, 0, stream>>>(xcur, tmp, l3g, l3b, (float*)d_out);
}